// Round 10
// baseline (649.371 us; speedup 1.0000x reference)
//
#include <hip/hip_runtime.h>

typedef unsigned short ushort_t;
typedef __attribute__((ext_vector_type(8))) short short8;
typedef __attribute__((ext_vector_type(4))) float float4_t;
typedef __attribute__((ext_vector_type(2))) float v2f;

// ---------- fast math helpers ----------
__device__ __forceinline__ float frcp(float x) { return __builtin_amdgcn_rcpf(x); }
__device__ __forceinline__ float fsig(float x) { return frcp(1.f + __expf(-x)); }
__device__ __forceinline__ float ftanh(float x) { return 1.f - 2.f * frcp(1.f + __expf(2.f * x)); }
// exp2-domain variants (argument pre-scaled by -log2e for sigmoid, +2log2e for tanh)
__device__ __forceinline__ float sig_e2(float a) { return frcp(1.f + __builtin_amdgcn_exp2f(a)); }
__device__ __forceinline__ float th_e2(float a) { return 1.f - 2.f * frcp(1.f + __builtin_amdgcn_exp2f(a)); }

__device__ __forceinline__ ushort_t f2bf(float f) {
    union { float f; unsigned u; } v; v.f = f;
    unsigned u = v.u;
    unsigned r = (u + 0x7fffu + ((u >> 16) & 1u)) >> 16;
    return (ushort_t)r;
}
__device__ __forceinline__ float bf2f(ushort_t s) {
    union { unsigned u; float f; } v; v.u = ((unsigned)s) << 16;
    return v.f;
}
// whole-wave shift-right-by-1 via DPP (lane0 gets 0). NOTE: must be used with
// FULL exec — a DPP read from an exec-disabled source lane returns 0, so never
// wrap this in a divergent ternary/branch (round-5 lesson).
__device__ __forceinline__ float dpp_shr1(float x) {
    int i = __builtin_bit_cast(int, x);
    int r = __builtin_amdgcn_update_dpp(0, i, 0x138 /*wave_shr:1*/, 0xf, 0xf, true);
    return __builtin_bit_cast(float, r);
}

// Barrier that drains ONLY LDS (lgkmcnt), NOT the global-store queue (vmcnt).
__device__ __forceinline__ void barrier_lds() {
    asm volatile("s_waitcnt lgkmcnt(0)" ::: "memory");
    __builtin_amdgcn_s_barrier();
    asm volatile("" ::: "memory");
}

// ---------------------------------------------------------------------------
// Block 0 MD-LSTM: C=2, Cin=1, H=64, W=256. Block per (dir,b) chain (64
// blocks -> 64 CUs), 128 threads = 2 waves, ONE UNIT PER WAVE. Units
// exchange h via a double-buffered LDS array with one lds-barrier per
// step. c stays register-local. Lane = row; h_u via (unconditional) DPP.
// ---------------------------------------------------------------------------
__global__ __launch_bounds__(128) void k_mdlstm0(
    const float* __restrict__ x, const float* __restrict__ Wx,
    const float* __restrict__ Wh, const float* __restrict__ Wv,
    const float* __restrict__ bias, float* __restrict__ h0)
{
    const int dir = blockIdx.x >> 4, b = blockIdx.x & 15;
    const int tid = threadIdx.x;
    const int u = tid >> 6;                           // wave index = unit
    const int lane = tid & 63;
    const bool fH = dir >= 2, fW = (dir & 1) != 0;
    const int ri = fH ? 63 - lane : lane;
    const float L2E = 1.44269504088896340736f;

    __shared__ float Xs[64 * 256];                    // 64 KB
    __shared__ float hbuf[2][2][64];                  // [parity][unit][lane]
    {
        const float* xg = x + b * 64 * 256;
        for (int i4 = tid; i4 < 4096; i4 += 128) {    // coalesced 16B loads
            int row = i4 >> 6, c4 = (i4 & 63) << 2;
            float4 v = *(const float4*)(xg + (row << 8) + c4);
            *(float4*)&Xs[(row << 8) + c4] = v;
        }
        for (int i = tid; i < 256; i += 128) ((float*)hbuf)[i] = 0.f;
    }
    __syncthreads();

    // Scalar weights for THIS unit's 5 gates. S = from own unit's h,
    // O = from other unit's h. Pre-scaled into exp2 domain.
    float wx[5], bs[5], whS[5], whO[5], wvS[5], wvO[5];
#pragma unroll
    for (int g = 0; g < 5; g++) {
        float sc = (g == 4) ? 2.f * L2E : -L2E;
        int n = g * 2 + u;
        wx[g]  = Wx[dir * 10 + n] * sc;
        bs[g]  = bias[dir * 10 + n] * sc;
        whS[g] = Wh[(dir * 2 + u) * 10 + n] * sc;
        whO[g] = Wh[(dir * 2 + (1 - u)) * 10 + n] * sc;
        wvS[g] = Wv[(dir * 2 + u) * 10 + n] * sc;
        wvO[g] = Wv[(dir * 2 + (1 - u)) * 10 + n] * sc;
    }

    float* orow = h0 + (((dir * 16 + b) * 64 + ri) * 256) * 2 + u;
    float hr = 0.f, cr = 0.f;

    auto ld = [&](int d) -> float {                   // LDS read of x
        int j = d - lane; j = j < 0 ? 0 : (j > 255 ? 255 : j);
        int cj = fW ? 255 - j : j;
        return Xs[(ri << 8) + cj];
    };
    float xp0 = ld(0), xp1 = ld(1);

    int p = 0;
    for (int d = 0; d < 319; d++) {
        float xv = xp0;
        xp0 = xp1;
        xp1 = ld(d + 2);                              // prefetch depth 2

        float ho  = hbuf[p][1 - u][lane];             // other unit h_l
        float hus = dpp_shr1(hr);                     // own unit h_u
        float cu  = dpp_shr1(cr);                     // own unit c_u
        float huo = dpp_shr1(ho);                     // other unit h_u

        int j = d - lane;
        if (j >= 0 && j < 256) {
            float a[5];
#pragma unroll
            for (int g = 0; g < 5; g++) {
                float t = fmaf(xv, wx[g], bs[g]);
                t = fmaf(hr,  whS[g], t);
                t = fmaf(ho,  whO[g], t);
                t = fmaf(hus, wvS[g], t);
                t = fmaf(huo, wvO[g], t);
                a[g] = t;
            }
            float si  = sig_e2(a[0]);
            float sf1 = sig_e2(a[1]);
            float sf2 = sig_e2(a[2]);
            float so  = sig_e2(a[3]);
            float tg  = th_e2(a[4]);
            float cn = si * tg + sf1 * cr + sf2 * cu;
            float tc = th_e2(cn * (2.f * L2E));
            hr = so * tc;
            cr = cn;
            int cj = fW ? 255 - j : j;
            orow[cj * 2] = hr;                        // fire-and-forget (no vmcnt drain)
        } else {
            hr = 0.f;                                 // keep inactive state 0
            cr = 0.f;
        }
        hbuf[1 - p][u][lane] = hr;                    // publish own h
        barrier_lds();
        p ^= 1;
    }
}

// ---------------------------------------------------------------------------
// conv0 (LDS-staged): h0 (sum 4 dirs) [64][64][256][2] -> conv(6,2,2,4) s2
// + tanh -> x1[32][127][16][6]. Block per (oh, b): 512 blocks, 256 thr.
// The 4dir x 2row input slab (16KB) is staged with fully-coalesced float4
// loads (each h0 element read exactly once), outputs computed from LDS.
// Replaces the old per-(oh,ow) version whose b-strided 8B loads were
// fully uncoalesced (~11 cache lines per wave-load).
// ---------------------------------------------------------------------------
__global__ __launch_bounds__(256) void k_conv0(
    const float* __restrict__ h0, const float* __restrict__ cw,
    const float* __restrict__ cb, float* __restrict__ x1)
{
    const int oh = blockIdx.x >> 4, b = blockIdx.x & 15;
    const int tid = threadIdx.x;

    __shared__ float hs[8][512];          // [dirb*2+kh][col*2+ci]  16 KB
    __shared__ float cws[192];            // conv weights

    // stage: 4096 floats = 1024 float4, coalesced
    for (int i4 = tid; i4 < 1024; i4 += 256) {
        int dk = i4 >> 7;                 // dirb*2+kh
        int c4 = (i4 & 127) << 2;
        const float* src = h0 + (((dk >> 1) * 16 + b) * 64 + (2 * oh + (dk & 1))) * 512 + c4;
        *(float4*)&hs[dk][c4] = *(const float4*)src;
    }
    if (tid < 192) cws[tid] = cw[tid];
    __syncthreads();

    for (int o = tid; o < 762; o += 256) {            // 127 ow x 6 co
        int ow = o / 6, co = o % 6;
        float acc = cb[co];
#pragma unroll
        for (int dirb = 0; dirb < 4; dirb++) {
#pragma unroll
            for (int kh = 0; kh < 2; kh++) {
                const float* hp = &hs[dirb * 2 + kh][0];
#pragma unroll
                for (int kw = 0; kw < 4; kw++) {
                    float2 hv = *(const float2*)&hp[(2 * ow + kw) * 2];
                    acc = fmaf(hv.x, cws[((co * 2 + 0) * 2 + kh) * 4 + kw], acc);
                    acc = fmaf(hv.y, cws[((co * 2 + 1) * 2 + kh) * 4 + kw], acc);
                }
            }
        }
        x1[((oh * 127 + ow) * 16 + b) * 6 + co] = ftanh(acc);
    }
}

// ---------------------------------------------------------------------------
// Block 1 MD-LSTM via MFMA: C=10, Cin=6, H=32, W=127. Block per (dir,b),
// 768 thr (12 waves). Whole x1-slice staged to LDS once (97.5KB); loop
// touches only LDS. 8 MFMA waves (2 m-tiles x 4 n-tiles), 3 mfma each
// (hi/lo split); tid 512-703 stage x for d+1; gate on tid<320.
// ---------------------------------------------------------------------------
__global__ __launch_bounds__(768, 1) void k_mdlstm1(
    const float* __restrict__ x1, const float* __restrict__ Wx,
    const float* __restrict__ Wh, const float* __restrict__ Wv,
    const float* __restrict__ bias, float* __restrict__ h1)
{
    const int dir = blockIdx.x >> 4, b = blockIdx.x & 15;
    const bool fH = dir >= 2, fW = (dir & 1) != 0;
    const int tid = threadIdx.x;
    const int wave = tid >> 6, lane = tid & 63;

    __shared__ float Xs1[32 * 127 * 6];           // 97.5 KB
    __shared__ __align__(16) ushort_t Ah[2][32][40];
    __shared__ __align__(16) ushort_t Al[2][32][40];
    __shared__ float P[32][68];
    __shared__ float cbuf[2][33][12];             // row 0 = permanent zeros

    for (int i = tid; i < 2 * 32 * 40; i += 768) { ((ushort_t*)Ah)[i] = 0; ((ushort_t*)Al)[i] = 0; }
    for (int i = tid; i < 2 * 33 * 12; i += 768) ((float*)cbuf)[i] = 0.f;
    for (int i = tid; i < 32 * 127 * 6; i += 768)
        Xs1[i] = x1[(i / 6) * 96 + b * 6 + (i % 6)];
    __syncthreads();
    if (tid < 6) {                                // x for step 0 (cell 0 only)
        int rr = fH ? 31 : 0, cc = fW ? 126 : 0;
        float xv = Xs1[(rr * 127 + cc) * 6 + tid];
        ushort_t xh = f2bf(xv);
        Ah[0][0][20 + tid] = xh;
        Al[0][0][20 + tid] = f2bf(xv - bf2f(xh));
    }

    // B fragments in regs: wave w -> mt = w&1 (rows), nt = w>>1 (gate cols)
    const int mt = wave & 1, nt = wave >> 1;
    short8 bh = {0,0,0,0,0,0,0,0}, bl = {0,0,0,0,0,0,0,0};
    if (wave < 8) {
        int n = nt * 16 + (lane & 15);
#pragma unroll
        for (int jj = 0; jj < 8; jj++) {
            int k = (lane >> 4) * 8 + jj;
            float v = 0.f;
            if (n < 50) {
                if (k < 10)      v = Wh[(dir * 10 + k) * 50 + n];
                else if (k < 20) v = Wv[(dir * 10 + (k - 10)) * 50 + n];
                else if (k < 26) v = Wx[(dir * 6 + (k - 20)) * 50 + n];
            }
            ushort_t hi = f2bf(v);
            bh[jj] = (short)hi;
            bl[jj] = (short)f2bf(v - bf2f(hi));
        }
    }

    const int cell = tid / 10, u = tid % 10;      // gate mapping (tid<320)
    float br[5];
#pragma unroll
    for (int g = 0; g < 5; g++) br[g] = (tid < 320) ? bias[dir * 50 + g * 10 + u] : 0.f;
    const int ri = fH ? 31 - cell : cell;
    float creg = 0.f;
    __syncthreads();

    int p = 0;
    for (int d = 0; d < 158; d++) {
        // ---- MFMA phase (waves 0-7) ----
        if (wave < 8) {
            const int arow = mt * 16 + (lane & 15);
            const int koff = (lane >> 4) * 8;
            short8 ah = *(const short8*)&Ah[p][arow][koff];
            short8 al = *(const short8*)&Al[p][arow][koff];
            float4_t acc = {0.f, 0.f, 0.f, 0.f};
            acc = __builtin_amdgcn_mfma_f32_16x16x32_bf16(ah, bh, acc, 0, 0, 0);
            acc = __builtin_amdgcn_mfma_f32_16x16x32_bf16(al, bh, acc, 0, 0, 0);
            acc = __builtin_amdgcn_mfma_f32_16x16x32_bf16(ah, bl, acc, 0, 0, 0);
            int col = nt * 16 + (lane & 15);
            int r0 = (lane >> 4) * 4;
#pragma unroll
            for (int r = 0; r < 4; r++) P[mt * 16 + r0 + r][col] = acc[r];
        } else if (tid >= 512 && tid < 704) {
            // ---- x-staging for step d+1 from LDS slice (overlaps MFMA) ----
            int s = tid - 512, xc = s / 6, ci = s % 6;
            int jn = d + 1 - xc;
            if (jn >= 0 && jn < 127) {
                int rr = fH ? 31 - xc : xc, cc = fW ? 126 - jn : jn;
                float xv = Xs1[(rr * 127 + cc) * 6 + ci];
                ushort_t xh = f2bf(xv);
                Ah[1 - p][xc][20 + ci] = xh;
                Al[1 - p][xc][20 + ci] = f2bf(xv - bf2f(xh));
            }
        }
        barrier_lds();

        // ---- gate phase (tid<320) ----
        if (tid < 320) {
            int j = d - cell;
            if (j >= 0 && j < 127) {
                float ai  = P[cell][u]      + br[0];
                float af1 = P[cell][10 + u] + br[1];
                float af2 = P[cell][20 + u] + br[2];
                float ao  = P[cell][30 + u] + br[3];
                float ag  = P[cell][40 + u] + br[4];
                float cu = cbuf[p][cell][u];
                float cn = fsig(ai) * ftanh(ag) + fsig(af1) * creg + fsig(af2) * cu;
                float hn = fsig(ao) * ftanh(cn);
                creg = cn;
                cbuf[1 - p][cell + 1][u] = cn;
                ushort_t hh = f2bf(hn);
                float hhf = bf2f(hh);
                ushort_t hlo = f2bf(hn - hhf);
                Ah[1 - p][cell][u] = hh;          // hl slot for next step
                Al[1 - p][cell][u] = hlo;
                if (cell < 31) { Ah[1 - p][cell + 1][10 + u] = hh; Al[1 - p][cell + 1][10 + u] = hlo; }
                int cj = fW ? 126 - j : j;
                h1[(((dir * 16 + b) * 32 + ri) * 127 + cj) * 10 + u] = hn;
            }
        }
        barrier_lds();
        p ^= 1;
    }
}

// ---------------------------------------------------------------------------
// conv1 (LDS-staged): h1 (sum 4 dirs) [64][32][127][10] -> conv(20,10,2,4)
// s2 + tanh -> x2[16][62][16][20]. Block per (oh, b): 256 blocks, 256 thr.
// 4dir x 2row slab (40.6KB) + weights (6.4KB) staged coalesced; outputs
// from LDS. Replaces the b-strided uncoalesced version.
// ---------------------------------------------------------------------------
__global__ __launch_bounds__(256) void k_conv1(
    const float* __restrict__ h1, const float* __restrict__ cw,
    const float* __restrict__ cb, float* __restrict__ x2)
{
    const int oh = blockIdx.x >> 4, b = blockIdx.x & 15;
    const int tid = threadIdx.x;

    __shared__ float hs[8][1270];         // [dirb*2+kh][col*10+ci]  40.6 KB
    __shared__ float cws[1600];           // conv weights 6.4 KB

    // stage rows: 10160 floats = 5080 float2, coalesced
    for (int i2 = tid; i2 < 5080; i2 += 256) {
        int dk = i2 / 635;                // dirb*2+kh
        int c2 = (i2 % 635) * 2;
        const float* src = h1 + (((dk >> 1) * 16 + b) * 32 + (2 * oh + (dk & 1))) * 1270 + c2;
        *(float2*)&hs[dk][c2] = *(const float2*)src;
    }
    for (int i = tid; i < 1600; i += 256) cws[i] = cw[i];
    __syncthreads();

    for (int o = tid; o < 1240; o += 256) {           // 62 ow x 20 co
        int ow = o / 20, co = o % 20;
        float acc = cb[co];
#pragma unroll
        for (int dirb = 0; dirb < 4; dirb++) {
#pragma unroll
            for (int kh = 0; kh < 2; kh++) {
                const float* hp = &hs[dirb * 2 + kh][0];
#pragma unroll
                for (int kw = 0; kw < 4; kw++) {
                    const float* hv = &hp[(2 * ow + kw) * 10];
#pragma unroll
                    for (int ci = 0; ci < 10; ci++)
                        acc = fmaf(hv[ci], cws[((co * 10 + ci) * 2 + kh) * 4 + kw], acc);
                }
            }
        }
        x2[((oh * 62 + ow) * 16 + b) * 20 + co] = ftanh(acc);
    }
}

// ---------------------------------------------------------------------------
// prep B for block2 MFMA, SPLIT hi/lo bf16:
// Bh/Bl[dir][k<128][n<256] = [Wh(50); Wv(50); Wx(20); 0pad]
// ---------------------------------------------------------------------------
__global__ __launch_bounds__(256) void k_prepB2(
    const float* __restrict__ Wh, const float* __restrict__ Wv,
    const float* __restrict__ Wx, ushort_t* __restrict__ Bh,
    ushort_t* __restrict__ Bl)
{
    int idx = blockIdx.x * 256 + threadIdx.x;      // 4*128*256 = 131072
    if (idx >= 131072) return;
    int dir = idx >> 15; int k = (idx >> 8) & 127; int n = idx & 255;
    float v = 0.f;
    if (n < 250) {
        if (k < 50)       v = Wh[(dir * 50 + k) * 250 + n];
        else if (k < 100) v = Wv[(dir * 50 + (k - 50)) * 250 + n];
        else if (k < 120) v = Wx[(dir * 20 + (k - 100)) * 250 + n];
    }
    ushort_t hi = f2bf(v);
    Bh[idx] = hi;
    Bl[idx] = f2bf(v - bf2f(hi));
}

// ---------------------------------------------------------------------------
// Block 2 MD-LSTM: C=50, Cin=20, H=16, W=62. Block per (dir,b), 832 thr
// (13 waves). 4 MFMA waves each compute 16 rows x 64 cols (B frags in
// 128 VGPRs); tid 256-575 stage x for step d+1 during the MFMA phase.
// Gate phase: 800 (cell,u) items on tid<800, ONE serial gate chain per
// thread (the old 512-thr version ran TWO chains on tid<288 — the second
// was pure critical path, ~300cy x 77 steps). In-loop barriers drain LDS
// only (global h2 stores fly free).
// ---------------------------------------------------------------------------
__global__ __launch_bounds__(832, 1) void k_mdlstm2(
    const float* __restrict__ x2, const ushort_t* __restrict__ BmH,
    const ushort_t* __restrict__ BmL,
    const float* __restrict__ bias, float* __restrict__ h2)
{
    const int dir = blockIdx.x >> 4, b = blockIdx.x & 15;
    const bool fH = dir >= 2, fW = (dir & 1) != 0;
    const int tid = threadIdx.x;
    const int wave = tid >> 6, lane = tid & 63;

    __shared__ float Xs2[16 * 62 * 20];           // 79.4 KB
    __shared__ __align__(16) ushort_t Ah[2][16][136];
    __shared__ __align__(16) ushort_t Al[2][16][136];
    __shared__ float P[16][260];
    __shared__ float cbuf[2][16][52];

    for (int i = tid; i < 2 * 16 * 136; i += 832) { ((ushort_t*)Ah)[i] = 0; ((ushort_t*)Al)[i] = 0; }
    for (int i = tid; i < 16 * 62 * 20; i += 832)
        Xs2[i] = x2[(i / 20) * 320 + b * 20 + (i % 20)];
    __syncthreads();
    if (tid < 20) {                                   // x for step 0 (cell 0 only)
        int ci = tid;
        int rr = fH ? 15 : 0, cc = fW ? 61 : 0;
        float xv = Xs2[(rr * 62 + cc) * 20 + ci];
        ushort_t xh = f2bf(xv);
        Ah[0][0][100 + ci] = xh;
        Al[0][0][100 + ci] = f2bf(xv - bf2f(xh));
    }

    // B fragments: wave w<4 owns cols [w*64, w*64+64): 4 n-tiles x 4 k-slices.
    short8 bfragH[4][4], bfragL[4][4];
    if (wave < 4) {
#pragma unroll
        for (int j = 0; j < 4; j++) {
            const int n = wave * 64 + j * 16 + (lane & 15);
#pragma unroll
            for (int q = 0; q < 4; q++) {
#pragma unroll
                for (int jj = 0; jj < 8; jj++) {
                    int k = q * 32 + (lane >> 4) * 8 + jj;
                    bfragH[j][q][jj] = (short)BmH[(dir * 128 + k) * 256 + n];
                    bfragL[j][q][jj] = (short)BmL[(dir * 128 + k) * 256 + n];
                }
            }
        }
    }

    // gate item: tid < 800, one (cell,u) each
    const int cell0 = tid / 50, u0 = tid % 50;
    float bA0 = 0, bA1 = 0, bA2 = 0, bA3 = 0, bA4 = 0;
    if (tid < 800) {
        bA0 = bias[dir * 250 + u0];
        bA1 = bias[dir * 250 + 50 + u0];
        bA2 = bias[dir * 250 + 100 + u0];
        bA3 = bias[dir * 250 + 150 + u0];
        bA4 = bias[dir * 250 + 200 + u0];
    }
    const int rrc0 = fH ? 15 - cell0 : cell0;
    float creg0 = 0.f;
    __syncthreads();

    int p = 0;
    for (int d = 0; d < 77; d++) {
        // ---- MFMA phase (waves 0-3) ∥ x-staging (tid 256-575) ----
        if (wave < 4) {
            const int arow = lane & 15;
            const int koff = (lane >> 4) * 8;
            short8 ah[4], al[4];
#pragma unroll
            for (int q = 0; q < 4; q++) {
                ah[q] = *(const short8*)&Ah[p][arow][q * 32 + koff];
                al[q] = *(const short8*)&Al[p][arow][q * 32 + koff];
            }
            float4_t acc[4];
#pragma unroll
            for (int j = 0; j < 4; j++) acc[j] = (float4_t){0.f, 0.f, 0.f, 0.f};
#pragma unroll
            for (int q = 0; q < 4; q++)
#pragma unroll
                for (int j = 0; j < 4; j++)
                    acc[j] = __builtin_amdgcn_mfma_f32_16x16x32_bf16(ah[q], bfragH[j][q], acc[j], 0, 0, 0);
#pragma unroll
            for (int q = 0; q < 4; q++)
#pragma unroll
                for (int j = 0; j < 4; j++)
                    acc[j] = __builtin_amdgcn_mfma_f32_16x16x32_bf16(al[q], bfragH[j][q], acc[j], 0, 0, 0);
#pragma unroll
            for (int q = 0; q < 4; q++)
#pragma unroll
                for (int j = 0; j < 4; j++)
                    acc[j] = __builtin_amdgcn_mfma_f32_16x16x32_bf16(ah[q], bfragL[j][q], acc[j], 0, 0, 0);
            const int r0 = (lane >> 4) * 4;
#pragma unroll
            for (int j = 0; j < 4; j++) {
                int col = wave * 64 + j * 16 + (lane & 15);
#pragma unroll
                for (int r = 0; r < 4; r++) P[r0 + r][col] = acc[j][r];
            }
        } else if (tid < 576) {
            // x-staging for step d+1: 320 items (16 cells x 20 ci), 1 each
            int item = tid - 256;
            int xc = item / 20, ci = item % 20;
            int jn = d + 1 - xc;
            if (jn >= 0 && jn < 62) {
                int rr = fH ? 15 - xc : xc, cc = fW ? 61 - jn : jn;
                float xv = Xs2[(rr * 62 + cc) * 20 + ci];
                ushort_t xh = f2bf(xv);
                Ah[1 - p][xc][100 + ci] = xh;
                Al[1 - p][xc][100 + ci] = f2bf(xv - bf2f(xh));
            }
        }
        barrier_lds();

        // ---- gate phase: one item per thread, tid<800 ----
        if (tid < 800) {
            int j = d - cell0;
            if (j >= 0 && j < 62) {
                float ai  = P[cell0][u0] + bA0;
                float af1 = P[cell0][50 + u0] + bA1;
                float af2 = P[cell0][100 + u0] + bA2;
                float ao  = P[cell0][150 + u0] + bA3;
                float ag  = P[cell0][200 + u0] + bA4;
                float cu = (cell0 == 0) ? 0.f : cbuf[p][cell0 - 1][u0];
                float cn = fsig(ai) * ftanh(ag) + fsig(af1) * creg0 + fsig(af2) * cu;
                float hn = fsig(ao) * ftanh(cn);
                creg0 = cn;
                cbuf[1 - p][cell0][u0] = cn;
                ushort_t hh = f2bf(hn);
                float hhf = bf2f(hh);
                ushort_t hlo = f2bf(hn - hhf);
                Ah[1 - p][cell0][u0] = hh;
                Al[1 - p][cell0][u0] = hlo;
                if (cell0 < 15) { Ah[1 - p][cell0 + 1][50 + u0] = hh; Al[1 - p][cell0 + 1][50 + u0] = hlo; }
                int cc = fW ? 61 - j : j;
                h2[(((dir * 16 + b) * 16 + rrc0) * 62 + cc) * 50 + u0] = hn;
            }
        }
        barrier_lds();
        p ^= 1;
    }
}

// ---------------------------------------------------------------------------
// final: out[b][r][c][n] = sum_{dir,cc} h2[dir][b][r][c][cc]*dW[dir][cc][n] + sum_dir db[dir][n]
// ---------------------------------------------------------------------------
__global__ __launch_bounds__(256) void k_final(
    const float* __restrict__ h2, const float* __restrict__ dW,
    const float* __restrict__ db, float* __restrict__ out)
{
    int blk = blockIdx.x;                  // 16*62
    int r = blk / 62, c = blk % 62;
    int t = threadIdx.x;
    __shared__ float hb[3200];             // [4][16][50]
    for (int i = t; i < 3200; i += 256) {
        int dirb = i / 800, rem = i % 800, b = rem / 50, u = rem % 50;
        hb[i] = h2[(((dirb * 16 + b) * 16 + r) * 62 + c) * 50 + u];
    }
    __syncthreads();
    for (int o = t; o < 1600; o += 256) {
        int b = o / 100, n = o % 100;
        float acc = db[n] + db[100 + n] + db[200 + n] + db[300 + n];
#pragma unroll
        for (int dirb = 0; dirb < 4; dirb++) {
            const float* hp = hb + (dirb * 16 + b) * 50;
            const float* wp = dW + dirb * 5000 + n;
#pragma unroll 10
            for (int cc2 = 0; cc2 < 50; cc2++)
                acc = fmaf(hp[cc2], wp[cc2 * 100], acc);
        }
        out[((b * 16 + r) * 62 + c) * 100 + n] = acc;
    }
}

// ---------------------------------------------------------------------------
extern "C" void kernel_launch(void* const* d_in, const int* in_sizes, int n_in,
                              void* d_out, int out_size, void* d_ws, size_t ws_size,
                              hipStream_t stream)
{
    const float* x     = (const float*)d_in[0];
    const float* p0_Wx = (const float*)d_in[1];
    const float* p0_Wh = (const float*)d_in[2];
    const float* p0_Wv = (const float*)d_in[3];
    const float* p0_b  = (const float*)d_in[4];
    const float* c0_w  = (const float*)d_in[5];
    const float* c0_b  = (const float*)d_in[6];
    const float* p1_Wx = (const float*)d_in[7];
    const float* p1_Wh = (const float*)d_in[8];
    const float* p1_Wv = (const float*)d_in[9];
    const float* p1_b  = (const float*)d_in[10];
    const float* c1_w  = (const float*)d_in[11];
    const float* c1_b  = (const float*)d_in[12];
    const float* p2_Wx = (const float*)d_in[13];
    const float* p2_Wh = (const float*)d_in[14];
    const float* p2_Wv = (const float*)d_in[15];
    const float* p2_b  = (const float*)d_in[16];
    const float* dW    = (const float*)d_in[17];
    const float* db    = (const float*)d_in[18];
    float* out = (float*)d_out;
    float* ws  = (float*)d_ws;

    float* h0 = ws;                        // 4*16*64*256*2  = 2,097,152 fl
    float* x1 = h0 + 2097152;              // 32*127*16*6    =   390,144 fl
    float* h1 = x1 + 390144;               // 4*16*32*127*10 = 2,600,960 fl
    float* x2 = h1 + 2600960;              // 16*62*16*20    =   317,440 fl
    float* h2 = x2 + 317440;               // 4*16*16*62*50  = 3,174,400 fl
    ushort_t* BmH = (ushort_t*)(h2 + 3174400); // 4*128*256 bf16
    ushort_t* BmL = BmH + 131072;              // 4*128*256 bf16

    k_prepB2<<<512, 256, 0, stream>>>(p2_Wh, p2_Wv, p2_Wx, BmH, BmL);
    k_mdlstm0<<<64, 128, 0, stream>>>(x, p0_Wx, p0_Wh, p0_Wv, p0_b, h0);
    k_conv0<<<32 * 16, 256, 0, stream>>>(h0, c0_w, c0_b, x1);
    k_mdlstm1<<<64, 768, 0, stream>>>(x1, p1_Wx, p1_Wh, p1_Wv, p1_b, h1);
    k_conv1<<<16 * 16, 256, 0, stream>>>(h1, c1_w, c1_b, x2);
    k_mdlstm2<<<64, 832, 0, stream>>>(x2, BmH, BmL, p2_b, h2);
    k_final<<<16 * 62, 256, 0, stream>>>(h2, dW, db, out);
}

// Round 11
// 466.366 us; speedup vs baseline: 1.3924x; 1.3924x over previous
//
#include <hip/hip_runtime.h>

typedef unsigned short ushort_t;
typedef __attribute__((ext_vector_type(8))) short short8;
typedef __attribute__((ext_vector_type(4))) float float4_t;
typedef __attribute__((ext_vector_type(2))) float v2f;

// ---------- fast math helpers ----------
__device__ __forceinline__ float frcp(float x) { return __builtin_amdgcn_rcpf(x); }
__device__ __forceinline__ float fsig(float x) { return frcp(1.f + __expf(-x)); }
__device__ __forceinline__ float ftanh(float x) { return 1.f - 2.f * frcp(1.f + __expf(2.f * x)); }
// exp2-domain variants (argument pre-scaled by -log2e for sigmoid, +2log2e for tanh)
__device__ __forceinline__ float sig_e2(float a) { return frcp(1.f + __builtin_amdgcn_exp2f(a)); }
__device__ __forceinline__ float th_e2(float a) { return 1.f - 2.f * frcp(1.f + __builtin_amdgcn_exp2f(a)); }

__device__ __forceinline__ ushort_t f2bf(float f) {
    union { float f; unsigned u; } v; v.f = f;
    unsigned u = v.u;
    unsigned r = (u + 0x7fffu + ((u >> 16) & 1u)) >> 16;
    return (ushort_t)r;
}
__device__ __forceinline__ float bf2f(ushort_t s) {
    union { unsigned u; float f; } v; v.u = ((unsigned)s) << 16;
    return v.f;
}
// whole-wave shift-right-by-1 via DPP (lane0 gets 0). NOTE: must be used with
// FULL exec — a DPP read from an exec-disabled source lane returns 0, so never
// wrap this in a divergent ternary/branch (round-5 lesson).
__device__ __forceinline__ float dpp_shr1(float x) {
    int i = __builtin_bit_cast(int, x);
    int r = __builtin_amdgcn_update_dpp(0, i, 0x138 /*wave_shr:1*/, 0xf, 0xf, true);
    return __builtin_bit_cast(float, r);
}

// Barrier that drains ONLY LDS (lgkmcnt), NOT the global-store queue (vmcnt).
__device__ __forceinline__ void barrier_lds() {
    asm volatile("s_waitcnt lgkmcnt(0)" ::: "memory");
    __builtin_amdgcn_s_barrier();
    asm volatile("" ::: "memory");
}

// ---------------------------------------------------------------------------
// Block 0 MD-LSTM: C=2, Cin=1, H=64, W=256. Block per (dir,b) chain (64
// blocks -> 64 CUs), 128 threads = 2 waves, ONE UNIT PER WAVE. Units
// exchange h via a double-buffered LDS array with one lds-barrier per
// step. c stays register-local. Lane = row; h_u via (unconditional) DPP.
// ---------------------------------------------------------------------------
__global__ __launch_bounds__(128) void k_mdlstm0(
    const float* __restrict__ x, const float* __restrict__ Wx,
    const float* __restrict__ Wh, const float* __restrict__ Wv,
    const float* __restrict__ bias, float* __restrict__ h0)
{
    const int dir = blockIdx.x >> 4, b = blockIdx.x & 15;
    const int tid = threadIdx.x;
    const int u = tid >> 6;                           // wave index = unit
    const int lane = tid & 63;
    const bool fH = dir >= 2, fW = (dir & 1) != 0;
    const int ri = fH ? 63 - lane : lane;
    const float L2E = 1.44269504088896340736f;

    __shared__ float Xs[64 * 256];                    // 64 KB
    __shared__ float hbuf[2][2][64];                  // [parity][unit][lane]
    {
        const float* xg = x + b * 64 * 256;
        for (int i4 = tid; i4 < 4096; i4 += 128) {    // coalesced 16B loads
            int row = i4 >> 6, c4 = (i4 & 63) << 2;
            float4 v = *(const float4*)(xg + (row << 8) + c4);
            *(float4*)&Xs[(row << 8) + c4] = v;
        }
        for (int i = tid; i < 256; i += 128) ((float*)hbuf)[i] = 0.f;
    }
    __syncthreads();

    // Scalar weights for THIS unit's 5 gates. S = from own unit's h,
    // O = from other unit's h. Pre-scaled into exp2 domain.
    float wx[5], bs[5], whS[5], whO[5], wvS[5], wvO[5];
#pragma unroll
    for (int g = 0; g < 5; g++) {
        float sc = (g == 4) ? 2.f * L2E : -L2E;
        int n = g * 2 + u;
        wx[g]  = Wx[dir * 10 + n] * sc;
        bs[g]  = bias[dir * 10 + n] * sc;
        whS[g] = Wh[(dir * 2 + u) * 10 + n] * sc;
        whO[g] = Wh[(dir * 2 + (1 - u)) * 10 + n] * sc;
        wvS[g] = Wv[(dir * 2 + u) * 10 + n] * sc;
        wvO[g] = Wv[(dir * 2 + (1 - u)) * 10 + n] * sc;
    }

    float* orow = h0 + (((dir * 16 + b) * 64 + ri) * 256) * 2 + u;
    float hr = 0.f, cr = 0.f;

    auto ld = [&](int d) -> float {                   // LDS read of x
        int j = d - lane; j = j < 0 ? 0 : (j > 255 ? 255 : j);
        int cj = fW ? 255 - j : j;
        return Xs[(ri << 8) + cj];
    };
    float xp0 = ld(0), xp1 = ld(1);

    int p = 0;
    for (int d = 0; d < 319; d++) {
        float xv = xp0;
        xp0 = xp1;
        xp1 = ld(d + 2);                              // prefetch depth 2

        float ho  = hbuf[p][1 - u][lane];             // other unit h_l
        float hus = dpp_shr1(hr);                     // own unit h_u
        float cu  = dpp_shr1(cr);                     // own unit c_u
        float huo = dpp_shr1(ho);                     // other unit h_u

        int j = d - lane;
        if (j >= 0 && j < 256) {
            float a[5];
#pragma unroll
            for (int g = 0; g < 5; g++) {
                float t = fmaf(xv, wx[g], bs[g]);
                t = fmaf(hr,  whS[g], t);
                t = fmaf(ho,  whO[g], t);
                t = fmaf(hus, wvS[g], t);
                t = fmaf(huo, wvO[g], t);
                a[g] = t;
            }
            float si  = sig_e2(a[0]);
            float sf1 = sig_e2(a[1]);
            float sf2 = sig_e2(a[2]);
            float so  = sig_e2(a[3]);
            float tg  = th_e2(a[4]);
            float cn = si * tg + sf1 * cr + sf2 * cu;
            float tc = th_e2(cn * (2.f * L2E));
            hr = so * tc;
            cr = cn;
            int cj = fW ? 255 - j : j;
            orow[cj * 2] = hr;                        // fire-and-forget (no vmcnt drain)
        } else {
            hr = 0.f;                                 // keep inactive state 0
            cr = 0.f;
        }
        hbuf[1 - p][u][lane] = hr;                    // publish own h
        barrier_lds();
        p ^= 1;
    }
}

// ---------------------------------------------------------------------------
// conv0 (LDS-staged): h0 (sum 4 dirs) [64][64][256][2] -> conv(6,2,2,4) s2
// + tanh -> x1[32][127][16][6]. Block per (oh, b): 512 blocks, 256 thr.
// The 4dir x 2row input slab (16KB) is staged with fully-coalesced float4
// loads (each h0 element read exactly once), outputs computed from LDS.
// (Round-10: convs measured ~23us faster than the b-strided versions.)
// ---------------------------------------------------------------------------
__global__ __launch_bounds__(256) void k_conv0(
    const float* __restrict__ h0, const float* __restrict__ cw,
    const float* __restrict__ cb, float* __restrict__ x1)
{
    const int oh = blockIdx.x >> 4, b = blockIdx.x & 15;
    const int tid = threadIdx.x;

    __shared__ float hs[8][512];          // [dirb*2+kh][col*2+ci]  16 KB
    __shared__ float cws[192];            // conv weights

    // stage: 4096 floats = 1024 float4, coalesced
    for (int i4 = tid; i4 < 1024; i4 += 256) {
        int dk = i4 >> 7;                 // dirb*2+kh
        int c4 = (i4 & 127) << 2;
        const float* src = h0 + (((dk >> 1) * 16 + b) * 64 + (2 * oh + (dk & 1))) * 512 + c4;
        *(float4*)&hs[dk][c4] = *(const float4*)src;
    }
    if (tid < 192) cws[tid] = cw[tid];
    __syncthreads();

    for (int o = tid; o < 762; o += 256) {            // 127 ow x 6 co
        int ow = o / 6, co = o % 6;
        float acc = cb[co];
#pragma unroll
        for (int dirb = 0; dirb < 4; dirb++) {
#pragma unroll
            for (int kh = 0; kh < 2; kh++) {
                const float* hp = &hs[dirb * 2 + kh][0];
#pragma unroll
                for (int kw = 0; kw < 4; kw++) {
                    float2 hv = *(const float2*)&hp[(2 * ow + kw) * 2];
                    acc = fmaf(hv.x, cws[((co * 2 + 0) * 2 + kh) * 4 + kw], acc);
                    acc = fmaf(hv.y, cws[((co * 2 + 1) * 2 + kh) * 4 + kw], acc);
                }
            }
        }
        x1[((oh * 127 + ow) * 16 + b) * 6 + co] = ftanh(acc);
    }
}

// ---------------------------------------------------------------------------
// Block 1 MD-LSTM via MFMA: C=10, Cin=6, H=32, W=127. Block per (dir,b),
// 768 thr (12 waves). Whole x1-slice staged to LDS once (97.5KB); loop
// touches only LDS. 8 MFMA waves (2 m-tiles x 4 n-tiles), 3 mfma each
// (hi/lo split); tid 512-703 stage x for d+1; gate on tid<320.
// ---------------------------------------------------------------------------
__global__ __launch_bounds__(768, 1) void k_mdlstm1(
    const float* __restrict__ x1, const float* __restrict__ Wx,
    const float* __restrict__ Wh, const float* __restrict__ Wv,
    const float* __restrict__ bias, float* __restrict__ h1)
{
    const int dir = blockIdx.x >> 4, b = blockIdx.x & 15;
    const bool fH = dir >= 2, fW = (dir & 1) != 0;
    const int tid = threadIdx.x;
    const int wave = tid >> 6, lane = tid & 63;

    __shared__ float Xs1[32 * 127 * 6];           // 97.5 KB
    __shared__ __align__(16) ushort_t Ah[2][32][40];
    __shared__ __align__(16) ushort_t Al[2][32][40];
    __shared__ float P[32][68];
    __shared__ float cbuf[2][33][12];             // row 0 = permanent zeros

    for (int i = tid; i < 2 * 32 * 40; i += 768) { ((ushort_t*)Ah)[i] = 0; ((ushort_t*)Al)[i] = 0; }
    for (int i = tid; i < 2 * 33 * 12; i += 768) ((float*)cbuf)[i] = 0.f;
    for (int i = tid; i < 32 * 127 * 6; i += 768)
        Xs1[i] = x1[(i / 6) * 96 + b * 6 + (i % 6)];
    __syncthreads();
    if (tid < 6) {                                // x for step 0 (cell 0 only)
        int rr = fH ? 31 : 0, cc = fW ? 126 : 0;
        float xv = Xs1[(rr * 127 + cc) * 6 + tid];
        ushort_t xh = f2bf(xv);
        Ah[0][0][20 + tid] = xh;
        Al[0][0][20 + tid] = f2bf(xv - bf2f(xh));
    }

    // B fragments in regs: wave w -> mt = w&1 (rows), nt = w>>1 (gate cols)
    const int mt = wave & 1, nt = wave >> 1;
    short8 bh = {0,0,0,0,0,0,0,0}, bl = {0,0,0,0,0,0,0,0};
    if (wave < 8) {
        int n = nt * 16 + (lane & 15);
#pragma unroll
        for (int jj = 0; jj < 8; jj++) {
            int k = (lane >> 4) * 8 + jj;
            float v = 0.f;
            if (n < 50) {
                if (k < 10)      v = Wh[(dir * 10 + k) * 50 + n];
                else if (k < 20) v = Wv[(dir * 10 + (k - 10)) * 50 + n];
                else if (k < 26) v = Wx[(dir * 6 + (k - 20)) * 50 + n];
            }
            ushort_t hi = f2bf(v);
            bh[jj] = (short)hi;
            bl[jj] = (short)f2bf(v - bf2f(hi));
        }
    }

    const int cell = tid / 10, u = tid % 10;      // gate mapping (tid<320)
    float br[5];
#pragma unroll
    for (int g = 0; g < 5; g++) br[g] = (tid < 320) ? bias[dir * 50 + g * 10 + u] : 0.f;
    const int ri = fH ? 31 - cell : cell;
    float creg = 0.f;
    __syncthreads();

    int p = 0;
    for (int d = 0; d < 158; d++) {
        // ---- MFMA phase (waves 0-7) ----
        if (wave < 8) {
            const int arow = mt * 16 + (lane & 15);
            const int koff = (lane >> 4) * 8;
            short8 ah = *(const short8*)&Ah[p][arow][koff];
            short8 al = *(const short8*)&Al[p][arow][koff];
            float4_t acc = {0.f, 0.f, 0.f, 0.f};
            acc = __builtin_amdgcn_mfma_f32_16x16x32_bf16(ah, bh, acc, 0, 0, 0);
            acc = __builtin_amdgcn_mfma_f32_16x16x32_bf16(al, bh, acc, 0, 0, 0);
            acc = __builtin_amdgcn_mfma_f32_16x16x32_bf16(ah, bl, acc, 0, 0, 0);
            int col = nt * 16 + (lane & 15);
            int r0 = (lane >> 4) * 4;
#pragma unroll
            for (int r = 0; r < 4; r++) P[mt * 16 + r0 + r][col] = acc[r];
        } else if (tid >= 512 && tid < 704) {
            // ---- x-staging for step d+1 from LDS slice (overlaps MFMA) ----
            int s = tid - 512, xc = s / 6, ci = s % 6;
            int jn = d + 1 - xc;
            if (jn >= 0 && jn < 127) {
                int rr = fH ? 31 - xc : xc, cc = fW ? 126 - jn : jn;
                float xv = Xs1[(rr * 127 + cc) * 6 + ci];
                ushort_t xh = f2bf(xv);
                Ah[1 - p][xc][20 + ci] = xh;
                Al[1 - p][xc][20 + ci] = f2bf(xv - bf2f(xh));
            }
        }
        barrier_lds();

        // ---- gate phase (tid<320) ----
        if (tid < 320) {
            int j = d - cell;
            if (j >= 0 && j < 127) {
                float ai  = P[cell][u]      + br[0];
                float af1 = P[cell][10 + u] + br[1];
                float af2 = P[cell][20 + u] + br[2];
                float ao  = P[cell][30 + u] + br[3];
                float ag  = P[cell][40 + u] + br[4];
                float cu = cbuf[p][cell][u];
                float cn = fsig(ai) * ftanh(ag) + fsig(af1) * creg + fsig(af2) * cu;
                float hn = fsig(ao) * ftanh(cn);
                creg = cn;
                cbuf[1 - p][cell + 1][u] = cn;
                ushort_t hh = f2bf(hn);
                float hhf = bf2f(hh);
                ushort_t hlo = f2bf(hn - hhf);
                Ah[1 - p][cell][u] = hh;          // hl slot for next step
                Al[1 - p][cell][u] = hlo;
                if (cell < 31) { Ah[1 - p][cell + 1][10 + u] = hh; Al[1 - p][cell + 1][10 + u] = hlo; }
                int cj = fW ? 126 - j : j;
                h1[(((dir * 16 + b) * 32 + ri) * 127 + cj) * 10 + u] = hn;
            }
        }
        barrier_lds();
        p ^= 1;
    }
}

// ---------------------------------------------------------------------------
// conv1 (LDS-staged): h1 (sum 4 dirs) [64][32][127][10] -> conv(20,10,2,4)
// s2 + tanh -> x2[16][62][16][20]. Block per (oh, b): 256 blocks, 256 thr.
// 4dir x 2row slab (40.6KB) + weights (6.4KB) staged coalesced; outputs
// from LDS.
// ---------------------------------------------------------------------------
__global__ __launch_bounds__(256) void k_conv1(
    const float* __restrict__ h1, const float* __restrict__ cw,
    const float* __restrict__ cb, float* __restrict__ x2)
{
    const int oh = blockIdx.x >> 4, b = blockIdx.x & 15;
    const int tid = threadIdx.x;

    __shared__ float hs[8][1270];         // [dirb*2+kh][col*10+ci]  40.6 KB
    __shared__ float cws[1600];           // conv weights 6.4 KB

    // stage rows: 10160 floats = 5080 float2, coalesced
    for (int i2 = tid; i2 < 5080; i2 += 256) {
        int dk = i2 / 635;                // dirb*2+kh
        int c2 = (i2 % 635) * 2;
        const float* src = h1 + (((dk >> 1) * 16 + b) * 32 + (2 * oh + (dk & 1))) * 1270 + c2;
        *(float2*)&hs[dk][c2] = *(const float2*)src;
    }
    for (int i = tid; i < 1600; i += 256) cws[i] = cw[i];
    __syncthreads();

    for (int o = tid; o < 1240; o += 256) {           // 62 ow x 20 co
        int ow = o / 20, co = o % 20;
        float acc = cb[co];
#pragma unroll
        for (int dirb = 0; dirb < 4; dirb++) {
#pragma unroll
            for (int kh = 0; kh < 2; kh++) {
                const float* hp = &hs[dirb * 2 + kh][0];
#pragma unroll
                for (int kw = 0; kw < 4; kw++) {
                    const float* hv = &hp[(2 * ow + kw) * 10];
#pragma unroll
                    for (int ci = 0; ci < 10; ci++)
                        acc = fmaf(hv[ci], cws[((co * 10 + ci) * 2 + kh) * 4 + kw], acc);
                }
            }
        }
        x2[((oh * 62 + ow) * 16 + b) * 20 + co] = ftanh(acc);
    }
}

// ---------------------------------------------------------------------------
// prep B for block2 MFMA, SPLIT hi/lo bf16:
// Bh/Bl[dir][k<128][n<256] = [Wh(50); Wv(50); Wx(20); 0pad]
// ---------------------------------------------------------------------------
__global__ __launch_bounds__(256) void k_prepB2(
    const float* __restrict__ Wh, const float* __restrict__ Wv,
    const float* __restrict__ Wx, ushort_t* __restrict__ Bh,
    ushort_t* __restrict__ Bl)
{
    int idx = blockIdx.x * 256 + threadIdx.x;      // 4*128*256 = 131072
    if (idx >= 131072) return;
    int dir = idx >> 15; int k = (idx >> 8) & 127; int n = idx & 255;
    float v = 0.f;
    if (n < 250) {
        if (k < 50)       v = Wh[(dir * 50 + k) * 250 + n];
        else if (k < 100) v = Wv[(dir * 50 + (k - 50)) * 250 + n];
        else if (k < 120) v = Wx[(dir * 20 + (k - 100)) * 250 + n];
    }
    ushort_t hi = f2bf(v);
    Bh[idx] = hi;
    Bl[idx] = f2bf(v - bf2f(hi));
}

// ---------------------------------------------------------------------------
// Block 2 MD-LSTM: C=50, Cin=20, H=16, W=62. Block per (dir,b), 512 thr
// (8 waves) — EXACT Round-8 shape (101us, VGPR=128, no spill). Round-10's
// 832-thread variant made the compiler cap VGPRs at 64 -> 256 VGPRs of
// B-fragments spilled to scratch (WRITE_SIZE 13->41MB, 295us). 4 MFMA
// waves each compute 16 rows x 64 cols (B frags in 128 VGPRs); waves 4-7
// stage x for step d+1. Gate phase: 800 items on 512 threads (2 items for
// tid<288). In-loop barriers drain LDS only.
// ---------------------------------------------------------------------------
__global__ __launch_bounds__(512, 1) void k_mdlstm2(
    const float* __restrict__ x2, const ushort_t* __restrict__ BmH,
    const ushort_t* __restrict__ BmL,
    const float* __restrict__ bias, float* __restrict__ h2)
{
    const int dir = blockIdx.x >> 4, b = blockIdx.x & 15;
    const bool fH = dir >= 2, fW = (dir & 1) != 0;
    const int tid = threadIdx.x;
    const int wave = tid >> 6, lane = tid & 63;

    __shared__ float Xs2[16 * 62 * 20];           // 79.4 KB
    __shared__ __align__(16) ushort_t Ah[2][16][136];
    __shared__ __align__(16) ushort_t Al[2][16][136];
    __shared__ float P[16][260];
    __shared__ float cbuf[2][16][52];

    for (int i = tid; i < 2 * 16 * 136; i += 512) { ((ushort_t*)Ah)[i] = 0; ((ushort_t*)Al)[i] = 0; }
    for (int i = tid; i < 16 * 62 * 20; i += 512)
        Xs2[i] = x2[(i / 20) * 320 + b * 20 + (i % 20)];
    __syncthreads();
    if (tid < 20) {                                   // x for step 0 (cell 0 only)
        int ci = tid;
        int rr = fH ? 15 : 0, cc = fW ? 61 : 0;
        float xv = Xs2[(rr * 62 + cc) * 20 + ci];
        ushort_t xh = f2bf(xv);
        Ah[0][0][100 + ci] = xh;
        Al[0][0][100 + ci] = f2bf(xv - bf2f(xh));
    }

    // B fragments: wave w<4 owns cols [w*64, w*64+64): 4 n-tiles x 4 k-slices.
    short8 bfragH[4][4], bfragL[4][4];
    if (wave < 4) {
#pragma unroll
        for (int j = 0; j < 4; j++) {
            const int n = wave * 64 + j * 16 + (lane & 15);
#pragma unroll
            for (int q = 0; q < 4; q++) {
#pragma unroll
                for (int jj = 0; jj < 8; jj++) {
                    int k = q * 32 + (lane >> 4) * 8 + jj;
                    bfragH[j][q][jj] = (short)BmH[(dir * 128 + k) * 256 + n];
                    bfragL[j][q][jj] = (short)BmL[(dir * 128 + k) * 256 + n];
                }
            }
        }
    }

    // gate items: item0 = tid (all 512), item1 = 512+tid (tid<288)
    const int cell0 = tid / 50, u0 = tid % 50;
    const int cell1 = (512 + tid) / 50, u1 = (512 + tid) % 50;
    float bA0 = bias[dir * 250 + u0];
    float bA1 = bias[dir * 250 + 50 + u0];
    float bA2 = bias[dir * 250 + 100 + u0];
    float bA3 = bias[dir * 250 + 150 + u0];
    float bA4 = bias[dir * 250 + 200 + u0];
    float bB0 = 0, bB1 = 0, bB2 = 0, bB3 = 0, bB4 = 0;
    if (tid < 288) {
        bB0 = bias[dir * 250 + u1];
        bB1 = bias[dir * 250 + 50 + u1];
        bB2 = bias[dir * 250 + 100 + u1];
        bB3 = bias[dir * 250 + 150 + u1];
        bB4 = bias[dir * 250 + 200 + u1];
    }
    const int rrc0 = fH ? 15 - cell0 : cell0;
    const int rrc1 = fH ? 15 - cell1 : cell1;
    float creg0 = 0.f, creg1 = 0.f;
    __syncthreads();

    int p = 0;
    for (int d = 0; d < 77; d++) {
        // ---- MFMA phase (waves 0-3) ∥ x-staging (waves 4-7) ----
        if (wave < 4) {
            const int arow = lane & 15;
            const int koff = (lane >> 4) * 8;
            short8 ah[4], al[4];
#pragma unroll
            for (int q = 0; q < 4; q++) {
                ah[q] = *(const short8*)&Ah[p][arow][q * 32 + koff];
                al[q] = *(const short8*)&Al[p][arow][q * 32 + koff];
            }
            float4_t acc[4];
#pragma unroll
            for (int j = 0; j < 4; j++) acc[j] = (float4_t){0.f, 0.f, 0.f, 0.f};
#pragma unroll
            for (int q = 0; q < 4; q++)
#pragma unroll
                for (int j = 0; j < 4; j++)
                    acc[j] = __builtin_amdgcn_mfma_f32_16x16x32_bf16(ah[q], bfragH[j][q], acc[j], 0, 0, 0);
#pragma unroll
            for (int q = 0; q < 4; q++)
#pragma unroll
                for (int j = 0; j < 4; j++)
                    acc[j] = __builtin_amdgcn_mfma_f32_16x16x32_bf16(al[q], bfragH[j][q], acc[j], 0, 0, 0);
#pragma unroll
            for (int q = 0; q < 4; q++)
#pragma unroll
                for (int j = 0; j < 4; j++)
                    acc[j] = __builtin_amdgcn_mfma_f32_16x16x32_bf16(ah[q], bfragL[j][q], acc[j], 0, 0, 0);
            const int r0 = (lane >> 4) * 4;
#pragma unroll
            for (int j = 0; j < 4; j++) {
                int col = wave * 64 + j * 16 + (lane & 15);
#pragma unroll
                for (int r = 0; r < 4; r++) P[r0 + r][col] = acc[j][r];
            }
        } else {
            // x-staging for step d+1: 320 items (16 cells x 20 ci) on 256 thr
            int s = tid - 256;
#pragma unroll
            for (int it = 0; it < 2; it++) {
                int item = s + it * 256;
                if (item < 320) {
                    int xc = item / 20, ci = item % 20;
                    int jn = d + 1 - xc;
                    if (jn >= 0 && jn < 62) {
                        int rr = fH ? 15 - xc : xc, cc = fW ? 61 - jn : jn;
                        float xv = Xs2[(rr * 62 + cc) * 20 + ci];
                        ushort_t xh = f2bf(xv);
                        Ah[1 - p][xc][100 + ci] = xh;
                        Al[1 - p][xc][100 + ci] = f2bf(xv - bf2f(xh));
                    }
                }
            }
        }
        barrier_lds();

        // ---- gate phase: item0 on all 512 threads, item1 on tid<288 ----
        auto gate = [&](int j, int cell, int u, int rrc,
                        float g0, float g1, float g2, float g3, float g4,
                        float& creg) {
            float ai  = P[cell][u] + g0;
            float af1 = P[cell][50 + u] + g1;
            float af2 = P[cell][100 + u] + g2;
            float ao  = P[cell][150 + u] + g3;
            float ag  = P[cell][200 + u] + g4;
            float cu = (cell == 0) ? 0.f : cbuf[p][cell - 1][u];
            float cn = fsig(ai) * ftanh(ag) + fsig(af1) * creg + fsig(af2) * cu;
            float hn = fsig(ao) * ftanh(cn);
            creg = cn;
            cbuf[1 - p][cell][u] = cn;
            ushort_t hh = f2bf(hn);
            float hhf = bf2f(hh);
            ushort_t hlo = f2bf(hn - hhf);
            Ah[1 - p][cell][u] = hh;
            Al[1 - p][cell][u] = hlo;
            if (cell < 15) { Ah[1 - p][cell + 1][50 + u] = hh; Al[1 - p][cell + 1][50 + u] = hlo; }
            int cc = fW ? 61 - j : j;
            h2[(((dir * 16 + b) * 16 + rrc) * 62 + cc) * 50 + u] = hn;
        };
        {
            int j0 = d - cell0;
            if (j0 >= 0 && j0 < 62)
                gate(j0, cell0, u0, rrc0, bA0, bA1, bA2, bA3, bA4, creg0);
            if (tid < 288) {
                int j1 = d - cell1;
                if (j1 >= 0 && j1 < 62)
                    gate(j1, cell1, u1, rrc1, bB0, bB1, bB2, bB3, bB4, creg1);
            }
        }
        barrier_lds();
        p ^= 1;
    }
}

// ---------------------------------------------------------------------------
// final: out[b][r][c][n] = sum_{dir,cc} h2[dir][b][r][c][cc]*dW[dir][cc][n] + sum_dir db[dir][n]
// ---------------------------------------------------------------------------
__global__ __launch_bounds__(256) void k_final(
    const float* __restrict__ h2, const float* __restrict__ dW,
    const float* __restrict__ db, float* __restrict__ out)
{
    int blk = blockIdx.x;                  // 16*62
    int r = blk / 62, c = blk % 62;
    int t = threadIdx.x;
    __shared__ float hb[3200];             // [4][16][50]
    for (int i = t; i < 3200; i += 256) {
        int dirb = i / 800, rem = i % 800, b = rem / 50, u = rem % 50;
        hb[i] = h2[(((dirb * 16 + b) * 16 + r) * 62 + c) * 50 + u];
    }
    __syncthreads();
    for (int o = t; o < 1600; o += 256) {
        int b = o / 100, n = o % 100;
        float acc = db[n] + db[100 + n] + db[200 + n] + db[300 + n];
#pragma unroll
        for (int dirb = 0; dirb < 4; dirb++) {
            const float* hp = hb + (dirb * 16 + b) * 50;
            const float* wp = dW + dirb * 5000 + n;
#pragma unroll 10
            for (int cc2 = 0; cc2 < 50; cc2++)
                acc = fmaf(hp[cc2], wp[cc2 * 100], acc);
        }
        out[((b * 16 + r) * 62 + c) * 100 + n] = acc;
    }
}

// ---------------------------------------------------------------------------
extern "C" void kernel_launch(void* const* d_in, const int* in_sizes, int n_in,
                              void* d_out, int out_size, void* d_ws, size_t ws_size,
                              hipStream_t stream)
{
    const float* x     = (const float*)d_in[0];
    const float* p0_Wx = (const float*)d_in[1];
    const float* p0_Wh = (const float*)d_in[2];
    const float* p0_Wv = (const float*)d_in[3];
    const float* p0_b  = (const float*)d_in[4];
    const float* c0_w  = (const float*)d_in[5];
    const float* c0_b  = (const float*)d_in[6];
    const float* p1_Wx = (const float*)d_in[7];
    const float* p1_Wh = (const float*)d_in[8];
    const float* p1_Wv = (const float*)d_in[9];
    const float* p1_b  = (const float*)d_in[10];
    const float* c1_w  = (const float*)d_in[11];
    const float* c1_b  = (const float*)d_in[12];
    const float* p2_Wx = (const float*)d_in[13];
    const float* p2_Wh = (const float*)d_in[14];
    const float* p2_Wv = (const float*)d_in[15];
    const float* p2_b  = (const float*)d_in[16];
    const float* dW    = (const float*)d_in[17];
    const float* db    = (const float*)d_in[18];
    float* out = (float*)d_out;
    float* ws  = (float*)d_ws;

    float* h0 = ws;                        // 4*16*64*256*2  = 2,097,152 fl
    float* x1 = h0 + 2097152;              // 32*127*16*6    =   390,144 fl
    float* h1 = x1 + 390144;               // 4*16*32*127*10 = 2,600,960 fl
    float* x2 = h1 + 2600960;              // 16*62*16*20    =   317,440 fl
    float* h2 = x2 + 317440;               // 4*16*16*62*50  = 3,174,400 fl
    ushort_t* BmH = (ushort_t*)(h2 + 3174400); // 4*128*256 bf16
    ushort_t* BmL = BmH + 131072;              // 4*128*256 bf16

    k_prepB2<<<512, 256, 0, stream>>>(p2_Wh, p2_Wv, p2_Wx, BmH, BmL);
    k_mdlstm0<<<64, 128, 0, stream>>>(x, p0_Wx, p0_Wh, p0_Wv, p0_b, h0);
    k_conv0<<<32 * 16, 256, 0, stream>>>(h0, c0_w, c0_b, x1);
    k_mdlstm1<<<64, 768, 0, stream>>>(x1, p1_Wx, p1_Wh, p1_Wv, p1_b, h1);
    k_conv1<<<16 * 16, 256, 0, stream>>>(h1, c1_w, c1_b, x2);
    k_mdlstm2<<<64, 512, 0, stream>>>(x2, BmH, BmL, p2_b, h2);
    k_final<<<16 * 62, 256, 0, stream>>>(h2, dW, db, out);
}

// Round 12
// 462.911 us; speedup vs baseline: 1.4028x; 1.0075x over previous
//
#include <hip/hip_runtime.h>

typedef unsigned short ushort_t;
typedef __attribute__((ext_vector_type(8))) short short8;
typedef __attribute__((ext_vector_type(4))) float float4_t;
typedef __attribute__((ext_vector_type(2))) float v2f;

// ---------- fast math helpers ----------
__device__ __forceinline__ float frcp(float x) { return __builtin_amdgcn_rcpf(x); }
__device__ __forceinline__ float fsig(float x) { return frcp(1.f + __expf(-x)); }
__device__ __forceinline__ float ftanh(float x) { return 1.f - 2.f * frcp(1.f + __expf(2.f * x)); }
// exp2-domain variants (argument pre-scaled by -log2e for sigmoid, +2log2e for tanh)
__device__ __forceinline__ float sig_e2(float a) { return frcp(1.f + __builtin_amdgcn_exp2f(a)); }
__device__ __forceinline__ float th_e2(float a) { return 1.f - 2.f * frcp(1.f + __builtin_amdgcn_exp2f(a)); }

__device__ __forceinline__ ushort_t f2bf(float f) {
    union { float f; unsigned u; } v; v.f = f;
    unsigned u = v.u;
    unsigned r = (u + 0x7fffu + ((u >> 16) & 1u)) >> 16;
    return (ushort_t)r;
}
__device__ __forceinline__ float bf2f(ushort_t s) {
    union { unsigned u; float f; } v; v.u = ((unsigned)s) << 16;
    return v.f;
}
// whole-wave shift-right-by-1 via DPP (lane0 gets 0). NOTE: must be used with
// FULL exec — a DPP read from an exec-disabled source lane returns 0, so never
// wrap this in a divergent ternary/branch (round-5 lesson).
__device__ __forceinline__ float dpp_shr1(float x) {
    int i = __builtin_bit_cast(int, x);
    int r = __builtin_amdgcn_update_dpp(0, i, 0x138 /*wave_shr:1*/, 0xf, 0xf, true);
    return __builtin_bit_cast(float, r);
}

// Barrier that drains ONLY LDS (lgkmcnt), NOT the global-store queue (vmcnt).
__device__ __forceinline__ void barrier_lds() {
    asm volatile("s_waitcnt lgkmcnt(0)" ::: "memory");
    __builtin_amdgcn_s_barrier();
    asm volatile("" ::: "memory");
}

// ---------------------------------------------------------------------------
// Block 0 MD-LSTM: C=2, Cin=1, H=64, W=256. Block per (dir,b) chain (64
// blocks -> 64 CUs), 128 threads = 2 waves, ONE UNIT PER WAVE. Units
// exchange h via a double-buffered LDS array with one lds-barrier per
// step. c stays register-local. Lane = row; h_u via (unconditional) DPP.
// ---------------------------------------------------------------------------
__global__ __launch_bounds__(128) void k_mdlstm0(
    const float* __restrict__ x, const float* __restrict__ Wx,
    const float* __restrict__ Wh, const float* __restrict__ Wv,
    const float* __restrict__ bias, float* __restrict__ h0)
{
    const int dir = blockIdx.x >> 4, b = blockIdx.x & 15;
    const int tid = threadIdx.x;
    const int u = tid >> 6;                           // wave index = unit
    const int lane = tid & 63;
    const bool fH = dir >= 2, fW = (dir & 1) != 0;
    const int ri = fH ? 63 - lane : lane;
    const float L2E = 1.44269504088896340736f;

    __shared__ float Xs[64 * 256];                    // 64 KB
    __shared__ float hbuf[2][2][64];                  // [parity][unit][lane]
    {
        const float* xg = x + b * 64 * 256;
        for (int i4 = tid; i4 < 4096; i4 += 128) {    // coalesced 16B loads
            int row = i4 >> 6, c4 = (i4 & 63) << 2;
            float4 v = *(const float4*)(xg + (row << 8) + c4);
            *(float4*)&Xs[(row << 8) + c4] = v;
        }
        for (int i = tid; i < 256; i += 128) ((float*)hbuf)[i] = 0.f;
    }
    __syncthreads();

    // Scalar weights for THIS unit's 5 gates. S = from own unit's h,
    // O = from other unit's h. Pre-scaled into exp2 domain.
    float wx[5], bs[5], whS[5], whO[5], wvS[5], wvO[5];
#pragma unroll
    for (int g = 0; g < 5; g++) {
        float sc = (g == 4) ? 2.f * L2E : -L2E;
        int n = g * 2 + u;
        wx[g]  = Wx[dir * 10 + n] * sc;
        bs[g]  = bias[dir * 10 + n] * sc;
        whS[g] = Wh[(dir * 2 + u) * 10 + n] * sc;
        whO[g] = Wh[(dir * 2 + (1 - u)) * 10 + n] * sc;
        wvS[g] = Wv[(dir * 2 + u) * 10 + n] * sc;
        wvO[g] = Wv[(dir * 2 + (1 - u)) * 10 + n] * sc;
    }

    float* orow = h0 + (((dir * 16 + b) * 64 + ri) * 256) * 2 + u;
    float hr = 0.f, cr = 0.f;

    auto ld = [&](int d) -> float {                   // LDS read of x
        int j = d - lane; j = j < 0 ? 0 : (j > 255 ? 255 : j);
        int cj = fW ? 255 - j : j;
        return Xs[(ri << 8) + cj];
    };
    float xp0 = ld(0), xp1 = ld(1);

    int p = 0;
    for (int d = 0; d < 319; d++) {
        float xv = xp0;
        xp0 = xp1;
        xp1 = ld(d + 2);                              // prefetch depth 2

        float ho  = hbuf[p][1 - u][lane];             // other unit h_l
        float hus = dpp_shr1(hr);                     // own unit h_u
        float cu  = dpp_shr1(cr);                     // own unit c_u
        float huo = dpp_shr1(ho);                     // other unit h_u

        int j = d - lane;
        if (j >= 0 && j < 256) {
            float a[5];
#pragma unroll
            for (int g = 0; g < 5; g++) {
                float t = fmaf(xv, wx[g], bs[g]);
                t = fmaf(hr,  whS[g], t);
                t = fmaf(ho,  whO[g], t);
                t = fmaf(hus, wvS[g], t);
                t = fmaf(huo, wvO[g], t);
                a[g] = t;
            }
            float si  = sig_e2(a[0]);
            float sf1 = sig_e2(a[1]);
            float sf2 = sig_e2(a[2]);
            float so  = sig_e2(a[3]);
            float tg  = th_e2(a[4]);
            float cn = si * tg + sf1 * cr + sf2 * cu;
            float tc = th_e2(cn * (2.f * L2E));
            hr = so * tc;
            cr = cn;
            int cj = fW ? 255 - j : j;
            orow[cj * 2] = hr;                        // fire-and-forget (no vmcnt drain)
        } else {
            hr = 0.f;                                 // keep inactive state 0
            cr = 0.f;
        }
        hbuf[1 - p][u][lane] = hr;                    // publish own h
        barrier_lds();
        p ^= 1;
    }
}

// ---------------------------------------------------------------------------
// conv0 (LDS-staged) + prepB2 fused: blocks 0-511 do conv0 (block per
// (oh,b)); blocks 512-1023 do prepB2 (B-matrix hi/lo split for block-2
// MFMA). prepB2's output is only consumed by k_mdlstm2, which launches
// after this kernel completes — ordering preserved, one launch saved.
// ---------------------------------------------------------------------------
__global__ __launch_bounds__(256) void k_conv0(
    const float* __restrict__ h0, const float* __restrict__ cw,
    const float* __restrict__ cb, float* __restrict__ x1,
    const float* __restrict__ Wh2, const float* __restrict__ Wv2,
    const float* __restrict__ Wx2, ushort_t* __restrict__ Bh,
    ushort_t* __restrict__ Bl)
{
    const int tid = threadIdx.x;
    if (blockIdx.x >= 512) {
        // ---- prepB2: Bh/Bl[dir][k<128][n<256] = [Wh(50);Wv(50);Wx(20);0] ----
        int idx = (blockIdx.x - 512) * 256 + tid;     // 512*256 = 131072 exact
        int dir = idx >> 15; int k = (idx >> 8) & 127; int n = idx & 255;
        float v = 0.f;
        if (n < 250) {
            if (k < 50)       v = Wh2[(dir * 50 + k) * 250 + n];
            else if (k < 100) v = Wv2[(dir * 50 + (k - 50)) * 250 + n];
            else if (k < 120) v = Wx2[(dir * 20 + (k - 100)) * 250 + n];
        }
        ushort_t hi = f2bf(v);
        Bh[idx] = hi;
        Bl[idx] = f2bf(v - bf2f(hi));
        return;
    }

    const int oh = blockIdx.x >> 4, b = blockIdx.x & 15;

    __shared__ float hs[8][512];          // [dirb*2+kh][col*2+ci]  16 KB
    __shared__ float cws[192];            // conv weights

    // stage: 4096 floats = 1024 float4, coalesced
    for (int i4 = tid; i4 < 1024; i4 += 256) {
        int dk = i4 >> 7;                 // dirb*2+kh
        int c4 = (i4 & 127) << 2;
        const float* src = h0 + (((dk >> 1) * 16 + b) * 64 + (2 * oh + (dk & 1))) * 512 + c4;
        *(float4*)&hs[dk][c4] = *(const float4*)src;
    }
    if (tid < 192) cws[tid] = cw[tid];
    __syncthreads();

    for (int o = tid; o < 762; o += 256) {            // 127 ow x 6 co
        int ow = o / 6, co = o % 6;
        float acc = cb[co];
#pragma unroll
        for (int dirb = 0; dirb < 4; dirb++) {
#pragma unroll
            for (int kh = 0; kh < 2; kh++) {
                const float* hp = &hs[dirb * 2 + kh][0];
#pragma unroll
                for (int kw = 0; kw < 4; kw++) {
                    float2 hv = *(const float2*)&hp[(2 * ow + kw) * 2];
                    acc = fmaf(hv.x, cws[((co * 2 + 0) * 2 + kh) * 4 + kw], acc);
                    acc = fmaf(hv.y, cws[((co * 2 + 1) * 2 + kh) * 4 + kw], acc);
                }
            }
        }
        x1[((oh * 127 + ow) * 16 + b) * 6 + co] = ftanh(acc);
    }
}

// ---------------------------------------------------------------------------
// Block 1 MD-LSTM via MFMA: C=10, Cin=6, H=32, W=127. Block per (dir,b),
// 768 thr (12 waves). Whole x1-slice staged to LDS once (97.5KB); loop
// touches only LDS. 8 MFMA waves (2 m-tiles x 4 n-tiles), 3 mfma each
// (hi/lo split); tid 512-703 stage x for d+1; gate on tid<320.
// ---------------------------------------------------------------------------
__global__ __launch_bounds__(768, 1) void k_mdlstm1(
    const float* __restrict__ x1, const float* __restrict__ Wx,
    const float* __restrict__ Wh, const float* __restrict__ Wv,
    const float* __restrict__ bias, float* __restrict__ h1)
{
    const int dir = blockIdx.x >> 4, b = blockIdx.x & 15;
    const bool fH = dir >= 2, fW = (dir & 1) != 0;
    const int tid = threadIdx.x;
    const int wave = tid >> 6, lane = tid & 63;

    __shared__ float Xs1[32 * 127 * 6];           // 97.5 KB
    __shared__ __align__(16) ushort_t Ah[2][32][40];
    __shared__ __align__(16) ushort_t Al[2][32][40];
    __shared__ float P[32][68];
    __shared__ float cbuf[2][33][12];             // row 0 = permanent zeros

    for (int i = tid; i < 2 * 32 * 40; i += 768) { ((ushort_t*)Ah)[i] = 0; ((ushort_t*)Al)[i] = 0; }
    for (int i = tid; i < 2 * 33 * 12; i += 768) ((float*)cbuf)[i] = 0.f;
    for (int i = tid; i < 32 * 127 * 6; i += 768)
        Xs1[i] = x1[(i / 6) * 96 + b * 6 + (i % 6)];
    __syncthreads();
    if (tid < 6) {                                // x for step 0 (cell 0 only)
        int rr = fH ? 31 : 0, cc = fW ? 126 : 0;
        float xv = Xs1[(rr * 127 + cc) * 6 + tid];
        ushort_t xh = f2bf(xv);
        Ah[0][0][20 + tid] = xh;
        Al[0][0][20 + tid] = f2bf(xv - bf2f(xh));
    }

    // B fragments in regs: wave w -> mt = w&1 (rows), nt = w>>1 (gate cols)
    const int mt = wave & 1, nt = wave >> 1;
    short8 bh = {0,0,0,0,0,0,0,0}, bl = {0,0,0,0,0,0,0,0};
    if (wave < 8) {
        int n = nt * 16 + (lane & 15);
#pragma unroll
        for (int jj = 0; jj < 8; jj++) {
            int k = (lane >> 4) * 8 + jj;
            float v = 0.f;
            if (n < 50) {
                if (k < 10)      v = Wh[(dir * 10 + k) * 50 + n];
                else if (k < 20) v = Wv[(dir * 10 + (k - 10)) * 50 + n];
                else if (k < 26) v = Wx[(dir * 6 + (k - 20)) * 50 + n];
            }
            ushort_t hi = f2bf(v);
            bh[jj] = (short)hi;
            bl[jj] = (short)f2bf(v - bf2f(hi));
        }
    }

    const int cell = tid / 10, u = tid % 10;      // gate mapping (tid<320)
    float br[5];
#pragma unroll
    for (int g = 0; g < 5; g++) br[g] = (tid < 320) ? bias[dir * 50 + g * 10 + u] : 0.f;
    const int ri = fH ? 31 - cell : cell;
    float creg = 0.f;
    __syncthreads();

    int p = 0;
    for (int d = 0; d < 158; d++) {
        // ---- MFMA phase (waves 0-7) ----
        if (wave < 8) {
            const int arow = mt * 16 + (lane & 15);
            const int koff = (lane >> 4) * 8;
            short8 ah = *(const short8*)&Ah[p][arow][koff];
            short8 al = *(const short8*)&Al[p][arow][koff];
            float4_t acc = {0.f, 0.f, 0.f, 0.f};
            acc = __builtin_amdgcn_mfma_f32_16x16x32_bf16(ah, bh, acc, 0, 0, 0);
            acc = __builtin_amdgcn_mfma_f32_16x16x32_bf16(al, bh, acc, 0, 0, 0);
            acc = __builtin_amdgcn_mfma_f32_16x16x32_bf16(ah, bl, acc, 0, 0, 0);
            int col = nt * 16 + (lane & 15);
            int r0 = (lane >> 4) * 4;
#pragma unroll
            for (int r = 0; r < 4; r++) P[mt * 16 + r0 + r][col] = acc[r];
        } else if (tid >= 512 && tid < 704) {
            // ---- x-staging for step d+1 from LDS slice (overlaps MFMA) ----
            int s = tid - 512, xc = s / 6, ci = s % 6;
            int jn = d + 1 - xc;
            if (jn >= 0 && jn < 127) {
                int rr = fH ? 31 - xc : xc, cc = fW ? 126 - jn : jn;
                float xv = Xs1[(rr * 127 + cc) * 6 + ci];
                ushort_t xh = f2bf(xv);
                Ah[1 - p][xc][20 + ci] = xh;
                Al[1 - p][xc][20 + ci] = f2bf(xv - bf2f(xh));
            }
        }
        barrier_lds();

        // ---- gate phase (tid<320) ----
        if (tid < 320) {
            int j = d - cell;
            if (j >= 0 && j < 127) {
                float ai  = P[cell][u]      + br[0];
                float af1 = P[cell][10 + u] + br[1];
                float af2 = P[cell][20 + u] + br[2];
                float ao  = P[cell][30 + u] + br[3];
                float ag  = P[cell][40 + u] + br[4];
                float cu = cbuf[p][cell][u];
                float cn = fsig(ai) * ftanh(ag) + fsig(af1) * creg + fsig(af2) * cu;
                float hn = fsig(ao) * ftanh(cn);
                creg = cn;
                cbuf[1 - p][cell + 1][u] = cn;
                ushort_t hh = f2bf(hn);
                float hhf = bf2f(hh);
                ushort_t hlo = f2bf(hn - hhf);
                Ah[1 - p][cell][u] = hh;          // hl slot for next step
                Al[1 - p][cell][u] = hlo;
                if (cell < 31) { Ah[1 - p][cell + 1][10 + u] = hh; Al[1 - p][cell + 1][10 + u] = hlo; }
                int cj = fW ? 126 - j : j;
                h1[(((dir * 16 + b) * 32 + ri) * 127 + cj) * 10 + u] = hn;
            }
        }
        barrier_lds();
        p ^= 1;
    }
}

// ---------------------------------------------------------------------------
// conv1 (LDS-staged): h1 (sum 4 dirs) [64][32][127][10] -> conv(20,10,2,4)
// s2 + tanh -> x2[16][62][16][20]. Block per (oh, b): 256 blocks, 256 thr.
// 4dir x 2row slab (40.6KB) + weights (6.4KB) staged coalesced; outputs
// from LDS.
// ---------------------------------------------------------------------------
__global__ __launch_bounds__(256) void k_conv1(
    const float* __restrict__ h1, const float* __restrict__ cw,
    const float* __restrict__ cb, float* __restrict__ x2)
{
    const int oh = blockIdx.x >> 4, b = blockIdx.x & 15;
    const int tid = threadIdx.x;

    __shared__ float hs[8][1270];         // [dirb*2+kh][col*10+ci]  40.6 KB
    __shared__ float cws[1600];           // conv weights 6.4 KB

    // stage rows: 10160 floats = 5080 float2, coalesced
    for (int i2 = tid; i2 < 5080; i2 += 256) {
        int dk = i2 / 635;                // dirb*2+kh
        int c2 = (i2 % 635) * 2;
        const float* src = h1 + (((dk >> 1) * 16 + b) * 32 + (2 * oh + (dk & 1))) * 1270 + c2;
        *(float2*)&hs[dk][c2] = *(const float2*)src;
    }
    for (int i = tid; i < 1600; i += 256) cws[i] = cw[i];
    __syncthreads();

    for (int o = tid; o < 1240; o += 256) {           // 62 ow x 20 co
        int ow = o / 20, co = o % 20;
        float acc = cb[co];
#pragma unroll
        for (int dirb = 0; dirb < 4; dirb++) {
#pragma unroll
            for (int kh = 0; kh < 2; kh++) {
                const float* hp = &hs[dirb * 2 + kh][0];
#pragma unroll
                for (int kw = 0; kw < 4; kw++) {
                    const float* hv = &hp[(2 * ow + kw) * 10];
#pragma unroll
                    for (int ci = 0; ci < 10; ci++)
                        acc = fmaf(hv[ci], cws[((co * 10 + ci) * 2 + kh) * 4 + kw], acc);
                }
            }
        }
        x2[((oh * 62 + ow) * 16 + b) * 20 + co] = ftanh(acc);
    }
}

// ---------------------------------------------------------------------------
// Block 2 MD-LSTM: C=50, Cin=20, H=16, W=62. Block per (dir,b), 512 thr
// (8 waves) — proven shape (VGPR=128, no spill; 832-thread variant spilled
// B-frags at the 64-VGPR cap). 4 MFMA waves each compute 16 rows x 64 cols
// (B frags in 128 VGPRs); waves 4-7 stage x for step d+1. Gate phase: 800
// items on 512 threads (2 items for tid<288). In-loop barriers drain LDS
// only.
// ---------------------------------------------------------------------------
__global__ __launch_bounds__(512, 1) void k_mdlstm2(
    const float* __restrict__ x2, const ushort_t* __restrict__ BmH,
    const ushort_t* __restrict__ BmL,
    const float* __restrict__ bias, float* __restrict__ h2)
{
    const int dir = blockIdx.x >> 4, b = blockIdx.x & 15;
    const bool fH = dir >= 2, fW = (dir & 1) != 0;
    const int tid = threadIdx.x;
    const int wave = tid >> 6, lane = tid & 63;

    __shared__ float Xs2[16 * 62 * 20];           // 79.4 KB
    __shared__ __align__(16) ushort_t Ah[2][16][136];
    __shared__ __align__(16) ushort_t Al[2][16][136];
    __shared__ float P[16][260];
    __shared__ float cbuf[2][16][52];

    for (int i = tid; i < 2 * 16 * 136; i += 512) { ((ushort_t*)Ah)[i] = 0; ((ushort_t*)Al)[i] = 0; }
    for (int i = tid; i < 16 * 62 * 20; i += 512)
        Xs2[i] = x2[(i / 20) * 320 + b * 20 + (i % 20)];
    __syncthreads();
    if (tid < 20) {                                   // x for step 0 (cell 0 only)
        int ci = tid;
        int rr = fH ? 15 : 0, cc = fW ? 61 : 0;
        float xv = Xs2[(rr * 62 + cc) * 20 + ci];
        ushort_t xh = f2bf(xv);
        Ah[0][0][100 + ci] = xh;
        Al[0][0][100 + ci] = f2bf(xv - bf2f(xh));
    }

    // B fragments: wave w<4 owns cols [w*64, w*64+64): 4 n-tiles x 4 k-slices.
    short8 bfragH[4][4], bfragL[4][4];
    if (wave < 4) {
#pragma unroll
        for (int j = 0; j < 4; j++) {
            const int n = wave * 64 + j * 16 + (lane & 15);
#pragma unroll
            for (int q = 0; q < 4; q++) {
#pragma unroll
                for (int jj = 0; jj < 8; jj++) {
                    int k = q * 32 + (lane >> 4) * 8 + jj;
                    bfragH[j][q][jj] = (short)BmH[(dir * 128 + k) * 256 + n];
                    bfragL[j][q][jj] = (short)BmL[(dir * 128 + k) * 256 + n];
                }
            }
        }
    }

    // gate items: item0 = tid (all 512), item1 = 512+tid (tid<288)
    const int cell0 = tid / 50, u0 = tid % 50;
    const int cell1 = (512 + tid) / 50, u1 = (512 + tid) % 50;
    float bA0 = bias[dir * 250 + u0];
    float bA1 = bias[dir * 250 + 50 + u0];
    float bA2 = bias[dir * 250 + 100 + u0];
    float bA3 = bias[dir * 250 + 150 + u0];
    float bA4 = bias[dir * 250 + 200 + u0];
    float bB0 = 0, bB1 = 0, bB2 = 0, bB3 = 0, bB4 = 0;
    if (tid < 288) {
        bB0 = bias[dir * 250 + u1];
        bB1 = bias[dir * 250 + 50 + u1];
        bB2 = bias[dir * 250 + 100 + u1];
        bB3 = bias[dir * 250 + 150 + u1];
        bB4 = bias[dir * 250 + 200 + u1];
    }
    const int rrc0 = fH ? 15 - cell0 : cell0;
    const int rrc1 = fH ? 15 - cell1 : cell1;
    float creg0 = 0.f, creg1 = 0.f;
    __syncthreads();

    int p = 0;
    for (int d = 0; d < 77; d++) {
        // ---- MFMA phase (waves 0-3) ∥ x-staging (waves 4-7) ----
        if (wave < 4) {
            const int arow = lane & 15;
            const int koff = (lane >> 4) * 8;
            short8 ah[4], al[4];
#pragma unroll
            for (int q = 0; q < 4; q++) {
                ah[q] = *(const short8*)&Ah[p][arow][q * 32 + koff];
                al[q] = *(const short8*)&Al[p][arow][q * 32 + koff];
            }
            float4_t acc[4];
#pragma unroll
            for (int j = 0; j < 4; j++) acc[j] = (float4_t){0.f, 0.f, 0.f, 0.f};
#pragma unroll
            for (int q = 0; q < 4; q++)
#pragma unroll
                for (int j = 0; j < 4; j++)
                    acc[j] = __builtin_amdgcn_mfma_f32_16x16x32_bf16(ah[q], bfragH[j][q], acc[j], 0, 0, 0);
#pragma unroll
            for (int q = 0; q < 4; q++)
#pragma unroll
                for (int j = 0; j < 4; j++)
                    acc[j] = __builtin_amdgcn_mfma_f32_16x16x32_bf16(al[q], bfragH[j][q], acc[j], 0, 0, 0);
#pragma unroll
            for (int q = 0; q < 4; q++)
#pragma unroll
                for (int j = 0; j < 4; j++)
                    acc[j] = __builtin_amdgcn_mfma_f32_16x16x32_bf16(ah[q], bfragL[j][q], acc[j], 0, 0, 0);
            const int r0 = (lane >> 4) * 4;
#pragma unroll
            for (int j = 0; j < 4; j++) {
                int col = wave * 64 + j * 16 + (lane & 15);
#pragma unroll
                for (int r = 0; r < 4; r++) P[r0 + r][col] = acc[j][r];
            }
        } else {
            // x-staging for step d+1: 320 items (16 cells x 20 ci) on 256 thr
            int s = tid - 256;
#pragma unroll
            for (int it = 0; it < 2; it++) {
                int item = s + it * 256;
                if (item < 320) {
                    int xc = item / 20, ci = item % 20;
                    int jn = d + 1 - xc;
                    if (jn >= 0 && jn < 62) {
                        int rr = fH ? 15 - xc : xc, cc = fW ? 61 - jn : jn;
                        float xv = Xs2[(rr * 62 + cc) * 20 + ci];
                        ushort_t xh = f2bf(xv);
                        Ah[1 - p][xc][100 + ci] = xh;
                        Al[1 - p][xc][100 + ci] = f2bf(xv - bf2f(xh));
                    }
                }
            }
        }
        barrier_lds();

        // ---- gate phase: item0 on all 512 threads, item1 on tid<288 ----
        auto gate = [&](int j, int cell, int u, int rrc,
                        float g0, float g1, float g2, float g3, float g4,
                        float& creg) {
            float ai  = P[cell][u] + g0;
            float af1 = P[cell][50 + u] + g1;
            float af2 = P[cell][100 + u] + g2;
            float ao  = P[cell][150 + u] + g3;
            float ag  = P[cell][200 + u] + g4;
            float cu = (cell == 0) ? 0.f : cbuf[p][cell - 1][u];
            float cn = fsig(ai) * ftanh(ag) + fsig(af1) * creg + fsig(af2) * cu;
            float hn = fsig(ao) * ftanh(cn);
            creg = cn;
            cbuf[1 - p][cell][u] = cn;
            ushort_t hh = f2bf(hn);
            float hhf = bf2f(hh);
            ushort_t hlo = f2bf(hn - hhf);
            Ah[1 - p][cell][u] = hh;
            Al[1 - p][cell][u] = hlo;
            if (cell < 15) { Ah[1 - p][cell + 1][50 + u] = hh; Al[1 - p][cell + 1][50 + u] = hlo; }
            int cc = fW ? 61 - j : j;
            h2[(((dir * 16 + b) * 16 + rrc) * 62 + cc) * 50 + u] = hn;
        };
        {
            int j0 = d - cell0;
            if (j0 >= 0 && j0 < 62)
                gate(j0, cell0, u0, rrc0, bA0, bA1, bA2, bA3, bA4, creg0);
            if (tid < 288) {
                int j1 = d - cell1;
                if (j1 >= 0 && j1 < 62)
                    gate(j1, cell1, u1, rrc1, bB0, bB1, bB2, bB3, bB4, creg1);
            }
        }
        barrier_lds();
        p ^= 1;
    }
}

// ---------------------------------------------------------------------------
// final: out[b][r][c][n] = sum_{dir,cc} h2[dir][b][r][c][cc]*dW[dir][cc][n] + sum_dir db[dir][n]
// ---------------------------------------------------------------------------
__global__ __launch_bounds__(256) void k_final(
    const float* __restrict__ h2, const float* __restrict__ dW,
    const float* __restrict__ db, float* __restrict__ out)
{
    int blk = blockIdx.x;                  // 16*62
    int r = blk / 62, c = blk % 62;
    int t = threadIdx.x;
    __shared__ float hb[3200];             // [4][16][50]
    for (int i = t; i < 3200; i += 256) {
        int dirb = i / 800, rem = i % 800, b = rem / 50, u = rem % 50;
        hb[i] = h2[(((dirb * 16 + b) * 16 + r) * 62 + c) * 50 + u];
    }
    __syncthreads();
    for (int o = t; o < 1600; o += 256) {
        int b = o / 100, n = o % 100;
        float acc = db[n] + db[100 + n] + db[200 + n] + db[300 + n];
#pragma unroll
        for (int dirb = 0; dirb < 4; dirb++) {
            const float* hp = hb + (dirb * 16 + b) * 50;
            const float* wp = dW + dirb * 5000 + n;
#pragma unroll 10
            for (int cc2 = 0; cc2 < 50; cc2++)
                acc = fmaf(hp[cc2], wp[cc2 * 100], acc);
        }
        out[((b * 16 + r) * 62 + c) * 100 + n] = acc;
    }
}

// ---------------------------------------------------------------------------
extern "C" void kernel_launch(void* const* d_in, const int* in_sizes, int n_in,
                              void* d_out, int out_size, void* d_ws, size_t ws_size,
                              hipStream_t stream)
{
    const float* x     = (const float*)d_in[0];
    const float* p0_Wx = (const float*)d_in[1];
    const float* p0_Wh = (const float*)d_in[2];
    const float* p0_Wv = (const float*)d_in[3];
    const float* p0_b  = (const float*)d_in[4];
    const float* c0_w  = (const float*)d_in[5];
    const float* c0_b  = (const float*)d_in[6];
    const float* p1_Wx = (const float*)d_in[7];
    const float* p1_Wh = (const float*)d_in[8];
    const float* p1_Wv = (const float*)d_in[9];
    const float* p1_b  = (const float*)d_in[10];
    const float* c1_w  = (const float*)d_in[11];
    const float* c1_b  = (const float*)d_in[12];
    const float* p2_Wx = (const float*)d_in[13];
    const float* p2_Wh = (const float*)d_in[14];
    const float* p2_Wv = (const float*)d_in[15];
    const float* p2_b  = (const float*)d_in[16];
    const float* dW    = (const float*)d_in[17];
    const float* db    = (const float*)d_in[18];
    float* out = (float*)d_out;
    float* ws  = (float*)d_ws;

    float* h0 = ws;                        // 4*16*64*256*2  = 2,097,152 fl
    float* x1 = h0 + 2097152;              // 32*127*16*6    =   390,144 fl
    float* h1 = x1 + 390144;               // 4*16*32*127*10 = 2,600,960 fl
    float* x2 = h1 + 2600960;              // 16*62*16*20    =   317,440 fl
    float* h2 = x2 + 317440;               // 4*16*16*62*50  = 3,174,400 fl
    ushort_t* BmH = (ushort_t*)(h2 + 3174400); // 4*128*256 bf16
    ushort_t* BmL = BmH + 131072;              // 4*128*256 bf16

    k_mdlstm0<<<64, 128, 0, stream>>>(x, p0_Wx, p0_Wh, p0_Wv, p0_b, h0);
    k_conv0<<<1024, 256, 0, stream>>>(h0, c0_w, c0_b, x1,
                                      p2_Wh, p2_Wv, p2_Wx, BmH, BmL);
    k_mdlstm1<<<64, 768, 0, stream>>>(x1, p1_Wx, p1_Wh, p1_Wv, p1_b, h1);
    k_conv1<<<16 * 16, 256, 0, stream>>>(h1, c1_w, c1_b, x2);
    k_mdlstm2<<<64, 512, 0, stream>>>(x2, BmH, BmL, p2_b, h2);
    k_final<<<16 * 62, 256, 0, stream>>>(h2, dW, db, out);
}